// Round 4
// baseline (903.342 us; speedup 1.0000x reference)
//
#include <hip/hip_runtime.h>

#define BATCHN 131072
#define FD 512
#define F2 256
#define LDSTR 520   // fused LDS row stride (bf16 elems): 1040B = 65*16B, 260 dwords %32==4 -> conflict-free b128

typedef __bf16 bf16x8 __attribute__((ext_vector_type(8)));
typedef float f32x4 __attribute__((ext_vector_type(4)));

__device__ __forceinline__ ushort f2bf(float f) {
  union { float f; uint u; } c; c.f = f;
  uint u = c.u;
  u += 0x7FFFu + ((u >> 16) & 1u);   // RNE
  return (ushort)(u >> 16);
}

// ws layout (float offsets)
#define WS_STATS123 0        // 3*1024: per-e [sum512, sumsq512]
#define WS_S4 3072           // 64 slots * [sum256, sumsq256]
#define WS_SCSH123 35840     // 3*1024: per-e [scale512, shift512]
#define WS_SCSH4 38912       // [scale256, shift256]
#define WS_W4BF 39424        // ushort[256*512] = 65536 floats
// total ws: 104960 floats = 420 KB

// ---------------- stats for BN1/BN2/BN3 (linear biases cancel in BN) ----------------
__global__ __launch_bounds__(256) void k_stats123(
    const float* __restrict__ W1, const float* __restrict__ W2,
    const float* __restrict__ W3, const int* __restrict__ subj,
    const int* __restrict__ obj, const int* __restrict__ predi,
    float* __restrict__ stats)
{
  const int e = blockIdx.y;
  const float* W = (e == 0) ? W1 : (e == 1 ? W2 : W3);
  const int* idx = (e == 0) ? subj : (e == 1 ? obj : predi);
  __shared__ int idxL[256];
  __shared__ float redS[512], redQ[512];
  int t = threadIdx.x;
  int base = blockIdx.x * 256;
  idxL[t] = idx[base + t];
  redS[t] = 0.f; redS[t + 256] = 0.f; redQ[t] = 0.f; redQ[t + 256] = 0.f;
  __syncthreads();
  int c = t & 63, rg = t >> 6;   // each wave covers a full 2KB row; lane c -> feats [8c, 8c+8)
  float s[8], q[8];
  #pragma unroll
  for (int j = 0; j < 8; ++j) { s[j] = 0.f; q[j] = 0.f; }
  for (int r = rg; r < 256; r += 4) {
    const float* row = W + (size_t)idxL[r] * FD + c * 8;
    float4 va = *(const float4*)(row);
    float4 vb = *(const float4*)(row + 4);
    float x[8] = {va.x, va.y, va.z, va.w, vb.x, vb.y, vb.z, vb.w};
    #pragma unroll
    for (int j = 0; j < 8; ++j) { s[j] += x[j]; q[j] += x[j] * x[j]; }
  }
  #pragma unroll
  for (int j = 0; j < 8; ++j) {
    atomicAdd(&redS[c * 8 + j], s[j]);
    atomicAdd(&redQ[c * 8 + j], q[j]);
  }
  __syncthreads();
  float* se = stats + e * 1024;
  atomicAdd(&se[t],        redS[t]);
  atomicAdd(&se[t + 256],  redS[t + 256]);
  atomicAdd(&se[512 + t],  redQ[t]);
  atomicAdd(&se[768 + t],  redQ[t + 256]);
}

__global__ void k_fin123(const float* __restrict__ stats,
                         const float* __restrict__ g1, const float* __restrict__ be1,
                         const float* __restrict__ g2, const float* __restrict__ be2,
                         const float* __restrict__ g3, const float* __restrict__ be3,
                         float* __restrict__ scsh)
{
  int e = blockIdx.x, f = threadIdx.x;  // 3 x 512
  const float* g  = (e == 0) ? g1  : (e == 1 ? g2  : g3);
  const float* be = (e == 0) ? be1 : (e == 1 ? be2 : be3);
  float S = stats[e * 1024 + f], SS = stats[e * 1024 + 512 + f];
  const float invB = 1.f / (float)BATCHN;
  float mean = S * invB;
  float var  = SS * invB - mean * mean;
  if (!(var >= 0.f && var < 1e30f)) var = 1.f;        // no-op when healthy
  if (!(mean > -1e30f && mean < 1e30f)) mean = 0.f;
  float r = rsqrtf(var + 1e-5f);
  float sc = g[f] * r;
  scsh[e * 1024 + f]       = sc;
  scsh[e * 1024 + 512 + f] = be[f] - mean * sc;
}

// ---------------- convert W4 (fp32, 256x512) to bf16 in ws ----------------
__global__ __launch_bounds__(256) void k_convW4(const float* __restrict__ W4,
                                                ushort* __restrict__ w4bf)
{
  int i = (blockIdx.x * 256 + threadIdx.x) * 4;   // 128 blocks cover 131072 elems
  float4 v = *(const float4*)(W4 + i);
  ushort4 o = {f2bf(v.x), f2bf(v.y), f2bf(v.z), f2bf(v.w)};
  *(ushort4*)(w4bf + i) = o;
}

// Shared tile body: gathers 32 rows (fp32), builds fused (bf16) in LDS, runs 32x256x512 MFMA.
// acc[mi][ni] f32x4; C/D: col=lane&15, row=(lane>>4)*4+reg; wave w owns cols [64w, 64w+64)
__device__ __forceinline__ void tile_fused_gemm(
    const float* __restrict__ W1, const float* __restrict__ W2, const float* __restrict__ W3,
    const ushort* __restrict__ w4bf,
    const int* __restrict__ subj, const int* __restrict__ obj, const int* __restrict__ predi,
    const float* __restrict__ scsh, int rowBase, int t,
    ushort* fusedL, int (*idxL)[32], f32x4 acc[2][4])
{
  if (t < 32)      idxL[0][t]      = subj[rowBase + t];
  else if (t < 64) idxL[1][t - 32] = obj[rowBase + t - 32];
  else if (t < 96) idxL[2][t - 64] = predi[rowBase + t - 64];

  int c = t & 63, rg = t >> 6;
  float sc[3][8], sh[3][8];
  #pragma unroll
  for (int e = 0; e < 3; ++e)
    #pragma unroll
    for (int j = 0; j < 8; ++j) {
      sc[e][j] = scsh[e * 1024 + c * 8 + j];
      sh[e][j] = scsh[e * 1024 + 512 + c * 8 + j];
    }
  __syncthreads();

  // phase A: fused rows -> LDS (bf16); wave rg handles rows r%4==rg
  for (int r = rg; r < 32; r += 4) {
    const float* r1 = W1 + (size_t)idxL[0][r] * FD + c * 8;
    const float* r2 = W2 + (size_t)idxL[1][r] * FD + c * 8;
    const float* r3 = W3 + (size_t)idxL[2][r] * FD + c * 8;
    float4 a1 = *(const float4*)(r1), b1 = *(const float4*)(r1 + 4);
    float4 a2 = *(const float4*)(r2), b2 = *(const float4*)(r2 + 4);
    float4 a3 = *(const float4*)(r3), b3 = *(const float4*)(r3 + 4);
    float x1[8] = {a1.x, a1.y, a1.z, a1.w, b1.x, b1.y, b1.z, b1.w};
    float x2[8] = {a2.x, a2.y, a2.z, a2.w, b2.x, b2.y, b2.z, b2.w};
    float x3[8] = {a3.x, a3.y, a3.z, a3.w, b3.x, b3.y, b3.z, b3.w};
    union { ushort o[8]; uint4 v; } u;
    #pragma unroll
    for (int j = 0; j < 8; ++j) {
      float v = fmaxf(fmaf(sc[0][j], x1[j], sh[0][j]), 0.f)
              + fmaxf(fmaf(sc[1][j], x2[j], sh[1][j]), 0.f)
              + fmaxf(fmaf(sc[2][j], x3[j], sh[2][j]), 0.f);
      v = fminf(v, 60000.f);   // no-op when healthy
      u.o[j] = f2bf(v);
    }
    *(uint4*)&fusedL[r * LDSTR + c * 8] = u.v;
  }
  __syncthreads();

  // phase B: MFMA; wave w owns cols [64w, 64w+64)
  int w = t >> 6, lane = t & 63;
  int m = lane & 15, q = lane >> 4;
  #pragma unroll
  for (int mi = 0; mi < 2; ++mi)
    #pragma unroll
    for (int ni = 0; ni < 4; ++ni)
      acc[mi][ni] = (f32x4){0.f, 0.f, 0.f, 0.f};

  const ushort* w4p = w4bf + ((size_t)(64 * w + m)) * FD + q * 8;  // B[k][n]=W4[n][k]; n=lane&15, k=q*8+j
  const ushort* fpL = fusedL + m * LDSTR + q * 8;                  // A[m][k]

  for (int kk = 0; kk < 16; ++kk) {
    int kc = kk * 32;
    bf16x8 af0 = *(const bf16x8*)(fpL + kc);
    bf16x8 af1 = *(const bf16x8*)(fpL + 16 * LDSTR + kc);
    #pragma unroll
    for (int ni = 0; ni < 4; ++ni) {
      bf16x8 bfv = *(const bf16x8*)(w4p + ni * 16 * FD + kc);
      acc[0][ni] = __builtin_amdgcn_mfma_f32_16x16x32_bf16(af0, bfv, acc[0][ni], 0, 0, 0);
      acc[1][ni] = __builtin_amdgcn_mfma_f32_16x16x32_bf16(af1, bfv, acc[1][ni], 0, 0, 0);
    }
  }
}

// ---------------- pass 1: BN4 column stats of fused@W4^T (b4 cancels in BN4) ----------------
__global__ __launch_bounds__(256) void k_pass1(
    const float* __restrict__ W1, const float* __restrict__ W2, const float* __restrict__ W3,
    const ushort* __restrict__ w4bf,
    const int* __restrict__ subj, const int* __restrict__ obj, const int* __restrict__ predi,
    const float* __restrict__ scsh, float* __restrict__ s4)
{
  alignas(16) __shared__ ushort fusedL[32 * LDSTR];
  __shared__ int idxL[3][32];
  __shared__ float colSum[256], colSS[256];
  int t = threadIdx.x;
  colSum[t] = 0.f; colSS[t] = 0.f;
  f32x4 acc[2][4];
  tile_fused_gemm(W1, W2, W3, w4bf, subj, obj, predi, scsh, blockIdx.x * 32, t, fusedL, idxL, acc);

  int w = t >> 6, lane = t & 63, m = lane & 15;
  #pragma unroll
  for (int ni = 0; ni < 4; ++ni) {
    int col = 64 * w + 16 * ni + m;
    float s = 0.f, ss = 0.f;
    #pragma unroll
    for (int mi = 0; mi < 2; ++mi)
      #pragma unroll
      for (int rr = 0; rr < 4; ++rr) {
        float v = acc[mi][ni][rr];
        s += v; ss += v * v;
      }
    atomicAdd(&colSum[col], s);
    atomicAdd(&colSS[col], ss);
  }
  __syncthreads();
  int slot = blockIdx.x & 63;
  atomicAdd(&s4[slot * 512 + t],       colSum[t]);
  atomicAdd(&s4[slot * 512 + 256 + t], colSS[t]);
}

__global__ void k_fin4(const float* __restrict__ s4, const float* __restrict__ g4,
                       const float* __restrict__ be4, float* __restrict__ scsh4)
{
  int j = threadIdx.x;  // 256
  float S = 0.f, SS = 0.f;
  for (int sl = 0; sl < 64; ++sl) { S += s4[sl * 512 + j]; SS += s4[sl * 512 + 256 + j]; }
  const float invB = 1.f / (float)BATCHN;
  float mean = S * invB;
  float var  = SS * invB - mean * mean;
  if (!(var >= 0.f && var < 1e30f)) var = 1.f;
  if (!(mean > -1e30f && mean < 1e30f)) mean = 0.f;
  float r = rsqrtf(var + 1e-5f);
  float sc = g4[j] * r;
  scsh4[j]       = sc;
  scsh4[256 + j] = be4[j] - mean * sc;
}

// ---------------- pass 2: recompute tile, BN4+relu+dot(W5)+b5 -> logits (fp32) ----------------
__global__ __launch_bounds__(256) void k_pass2(
    const float* __restrict__ W1, const float* __restrict__ W2, const float* __restrict__ W3,
    const ushort* __restrict__ w4bf,
    const int* __restrict__ subj, const int* __restrict__ obj, const int* __restrict__ predi,
    const float* __restrict__ scsh, const float* __restrict__ scsh4,
    const float* __restrict__ W5, const float* __restrict__ b5,
    float* __restrict__ out)
{
  alignas(16) __shared__ ushort fusedL[32 * LDSTR];
  __shared__ int idxL[3][32];
  __shared__ float partials[4][32];
  int t = threadIdx.x;
  int rowBase = blockIdx.x * 32;
  f32x4 acc[2][4];
  tile_fused_gemm(W1, W2, W3, w4bf, subj, obj, predi, scsh, rowBase, t, fusedL, idxL, acc);

  int w = t >> 6, lane = t & 63, m = lane & 15, q = lane >> 4;
  float sc4v[4], sh4v[4], w5v[4];
  #pragma unroll
  for (int ni = 0; ni < 4; ++ni) {
    int col = 64 * w + 16 * ni + m;
    sc4v[ni] = scsh4[col];
    sh4v[ni] = scsh4[256 + col];
    w5v[ni]  = W5[col];
  }
  float rowAcc[8];  // [mi*4+rr] -> row-in-tile 16*mi + q*4 + rr
  #pragma unroll
  for (int j = 0; j < 8; ++j) rowAcc[j] = 0.f;
  #pragma unroll
  for (int ni = 0; ni < 4; ++ni)
    #pragma unroll
    for (int mi = 0; mi < 2; ++mi)
      #pragma unroll
      for (int rr = 0; rr < 4; ++rr) {
        float v = fmaxf(fmaf(sc4v[ni], acc[mi][ni][rr], sh4v[ni]), 0.f);
        rowAcc[mi * 4 + rr] += v * w5v[ni];
      }
  // reduce across the 16 lanes (m) sharing each (q,row)
  #pragma unroll
  for (int j = 0; j < 8; ++j) {
    #pragma unroll
    for (int off = 1; off < 16; off <<= 1)
      rowAcc[j] += __shfl_xor(rowAcc[j], off, 64);
  }
  if (m == 0) {
    #pragma unroll
    for (int mi = 0; mi < 2; ++mi)
      #pragma unroll
      for (int rr = 0; rr < 4; ++rr)
        partials[w][16 * mi + q * 4 + rr] = rowAcc[mi * 4 + rr];
  }
  __syncthreads();
  if (t < 32) {
    float r = partials[0][t] + partials[1][t] + partials[2][t] + partials[3][t];
    out[rowBase + t] = r + b5[0];
  }
}

extern "C" void kernel_launch(void* const* d_in, const int* in_sizes, int n_in,
                              void* d_out, int out_size, void* d_ws, size_t ws_size,
                              hipStream_t stream)
{
  const int* subj  = (const int*)d_in[0];
  const int* obj   = (const int*)d_in[1];
  const int* predi = (const int*)d_in[2];
  const float* W1  = (const float*)d_in[3];
  // b1/b2/b3/b4 cancel inside their BatchNorms — never read
  const float* g1  = (const float*)d_in[5];
  const float* be1 = (const float*)d_in[6];
  const float* W2  = (const float*)d_in[7];
  const float* g2  = (const float*)d_in[9];
  const float* be2 = (const float*)d_in[10];
  const float* W3  = (const float*)d_in[11];
  const float* g3  = (const float*)d_in[13];
  const float* be3 = (const float*)d_in[14];
  const float* W4  = (const float*)d_in[15];
  const float* g4  = (const float*)d_in[17];
  const float* be4 = (const float*)d_in[18];
  const float* W5  = (const float*)d_in[19];
  const float* b5  = (const float*)d_in[20];

  float* wsf = (float*)d_ws;
  ushort* w4bf = (ushort*)(wsf + WS_W4BF);
  float* out = (float*)d_out;

  hipMemsetAsync(d_ws, 0, WS_SCSH123 * 4, stream);  // zero stats123 + s4 slots
  k_stats123<<<dim3(512, 3, 1), 256, 0, stream>>>(W1, W2, W3, subj, obj, predi, wsf + WS_STATS123);
  k_fin123<<<3, 512, 0, stream>>>(wsf + WS_STATS123, g1, be1, g2, be2, g3, be3, wsf + WS_SCSH123);
  k_convW4<<<128, 256, 0, stream>>>(W4, w4bf);
  k_pass1<<<BATCHN / 32, 256, 0, stream>>>(W1, W2, W3, w4bf, subj, obj, predi,
                                           wsf + WS_SCSH123, wsf + WS_S4);
  k_fin4<<<1, 256, 0, stream>>>(wsf + WS_S4, g4, be4, wsf + WS_SCSH4);
  k_pass2<<<BATCHN / 32, 256, 0, stream>>>(W1, W2, W3, w4bf, subj, obj, predi,
                                           wsf + WS_SCSH123, wsf + WS_SCSH4, W5, b5, out);
}